// Round 7
// baseline (904.639 us; speedup 1.0000x reference)
//
#include <hip/hip_runtime.h>

static constexpr int T_STEPS = 512;
static constexpr int NBATCH  = 256;
static constexpr int DD      = 128;                         // C = D = K = 128
static constexpr long TND    = (long)T_STEPS * NBATCH * DD; // elems per output tensor

static constexpr int SDEPTH = 4;     // LDS h-ring depth (steps)
static constexpr int LROW   = 132;   // padded LDS row in dwords (528B = 33*16: 16B-aligned, banks spread)

typedef short bf16x8 __attribute__((ext_vector_type(8)));   // 8 bf16 in 4 VGPRs
typedef float f32x4  __attribute__((ext_vector_type(4)));
typedef unsigned u32x4 __attribute__((ext_vector_type(4)));

__device__ inline unsigned short f2bf(float f) {            // RNE fp32 -> bf16
  unsigned u = __builtin_bit_cast(unsigned, f);
  unsigned r = u + 0x7FFFu + ((u >> 16) & 1u);
  return (unsigned short)(r >> 16);
}

__device__ inline bf16x8 pack8(const float* s) {
  bf16x8 v;
#pragma unroll
  for (int i = 0; i < 8; ++i) v[i] = (short)f2bf(s[i]);
  return v;
}

// v_cvt_pk_bf16_f32: D.lo = bf16(lo), D.hi = bf16(hi), RNE (gfx950).
__device__ __forceinline__ unsigned cvtpk_bf16(float lo, float hi) {
  unsigned r;
  asm("v_cvt_pk_bf16_f32 %0, %1, %2" : "=v"(r) : "v"(lo), "v"(hi));
  return r;
}

// ---------------------------------------------------------------------------
// Pre-pass: x (f32, 64MB) -> bf16 (32MB), RNE — bitwise identical to the
// in-step pack it replaces. Output parked in the Y region (64MB), which is
// only overwritten by GEMM-Y after the scan has consumed it (same stream).
// ---------------------------------------------------------------------------
__global__ __launch_bounds__(256) void cvt_x_bf16(
    const float* __restrict__ x, unsigned short* __restrict__ xb, long n8) {
  long i = (long)blockIdx.x * 256 + threadIdx.x;
  const long stride = (long)gridDim.x * 256;
  for (; i < n8; i += stride) {
    const float* p = x + i * 8;
    f32x4 a = *(const f32x4*)p, b = *(const f32x4*)(p + 4);
    u32x4 u;
    u[0] = cvtpk_bf16(a[0], a[1]); u[1] = cvtpk_bf16(a[2], a[3]);
    u[2] = cvtpk_bf16(b[0], b[1]); u[3] = cvtpk_bf16(b[2], b[3]);
    *(u32x4*)(xb + i * 8) = u;
  }
}

// ---------------------------------------------------------------------------
// Phase 3: Y[M x 128] = A[M x 128] @ Wy^T + by, Wy as the A-operand so the
// D-layout gives per-lane contiguous k -> 8 f32x4 stores/tile. Bias = C-init.
// ---------------------------------------------------------------------------
__global__ __launch_bounds__(256) void gemm128_yT(
    const float* __restrict__ A, const float* __restrict__ W,
    const float* __restrict__ bias, float* __restrict__ O, int ntiles) {
  const int lane = threadIdx.x & 63;
  const int wib  = threadIdx.x >> 6;     // wave in block (0..3)
  const int m    = lane & 15;
  const int q    = lane >> 4;

  bf16x8 Wf[8][4];
#pragma unroll
  for (int j = 0; j < 8; ++j)
#pragma unroll
    for (int kq = 0; kq < 4; ++kq) {
      const float* p = W + (j * 16 + m) * DD + kq * 32 + q * 8;
      float t[8];
      *(float4*)&t[0] = *(const float4*)p;
      *(float4*)&t[4] = *(const float4*)(p + 4);
      Wf[j][kq] = pack8(t);
    }
  f32x4 bv4[8];
#pragma unroll
  for (int j = 0; j < 8; ++j) bv4[j] = *(const f32x4*)(bias + j * 16 + 4 * q);

  const int wglobal = blockIdx.x * 4 + wib;
  const int nwaves  = gridDim.x * 4;
  for (int tile = wglobal; tile < ntiles; tile += nwaves) {
    const long r0 = (long)tile * 16;

    bf16x8 af[4];
#pragma unroll
    for (int kq = 0; kq < 4; ++kq) {
      const float* p = A + (r0 + m) * DD + kq * 32 + q * 8;
      float t[8];
      *(float4*)&t[0] = *(const float4*)p;
      *(float4*)&t[4] = *(const float4*)(p + 4);
      af[kq] = pack8(t);
    }
    f32x4 acc[8];
#pragma unroll
    for (int j = 0; j < 8; ++j)
      acc[j] = __builtin_amdgcn_mfma_f32_16x16x32_bf16(Wf[j][0], af[0], bv4[j], 0, 0, 0);
#pragma unroll
    for (int kq = 1; kq < 4; ++kq)
#pragma unroll
      for (int j = 0; j < 8; ++j)
        acc[j] = __builtin_amdgcn_mfma_f32_16x16x32_bf16(Wf[j][kq], af[kq], acc[j], 0, 0, 0);

    float* op = O + (r0 + m) * DD + 4 * q;
#pragma unroll
    for (int j = 0; j < 8; ++j)
      *(f32x4*)(op + j * 16) = acc[j];
  }
}

// ---------------------------------------------------------------------------
// Phase 1+2 FUSED scan, v4: PRODUCER/CONSUMER split. Wave 0 runs the serial
// recurrence and writes h ONLY to an LDS ring (lgkmcnt domain, ~30cy WAR);
// waves 1-2 poll a produced-counter and do the coalesced fp32 global stores,
// absorbing all store-completion latency OFF the recurrence critical path.
// Theory being tested: R2/R4/R6's ~1500cy/step residual stall is store-WAR
// (s_waitcnt vmcnt before redefining store-source VGPRs each step).
// Scan wave's vmcnt now tracks only the 4-step-ahead x prefetch ring.
// h-recurrence (verified R2-R6): kappa-permuted Wh gather + cvt_pk feedback
// makes the step's D quads directly the next step's B-frags — no shuffle.
// ---------------------------------------------------------------------------
__global__ __launch_bounds__(192, 1) void rnn_scan_fused(
    const unsigned short* __restrict__ xbf, const float* __restrict__ Wx,
    const float* __restrict__ bx, const float* __restrict__ Wh,
    float* __restrict__ H /* [T][N][128] output: all_h */) {
  __shared__ __align__(16) float hbuf[SDEPTH][16 * LROW];   // ~33.8 KB
  __shared__ volatile unsigned produced;      // steps fully written to LDS
  __shared__ volatile unsigned consumed[2];   // steps fully read out, per consumer

  const int wave = threadIdx.x >> 6;
  const int lane = threadIdx.x & 63;

  if (threadIdx.x == 0) { produced = 0; consumed[0] = 0; consumed[1] = 0; }
  __syncthreads();   // only barrier in the kernel (flag init)

  const long stepN = (long)NBATCH * DD;

  if (wave == 0) {
    // ------------------------------ producer: the serial scan ------------
    const int m = lane & 15;
    const int q = lane >> 4;

    // Wx A-frags, standard slot k = 32kq + 8q + s
    bf16x8 Wxf[8][4];
#pragma unroll
    for (int j = 0; j < 8; ++j)
#pragma unroll
      for (int kq = 0; kq < 4; ++kq) {
        const float* p = Wx + (j * 16 + m) * DD + kq * 32 + q * 8;
        float t[8];
        *(float4*)&t[0] = *(const float4*)p;
        *(float4*)&t[4] = *(const float4*)(p + 4);
        Wxf[j][kq] = pack8(t);
      }
    // Wh A-frags with the q-dependent kappa gather
    bf16x8 Whf[8][4];
#pragma unroll
    for (int j = 0; j < 8; ++j)
#pragma unroll
      for (int kq = 0; kq < 4; ++kq) {
        const float* p = Wh + (j * 16 + m) * DD + kq * 32 + 4 * q;
        float t[8];
        *(float4*)&t[0] = *(const float4*)p;
        *(float4*)&t[4] = *(const float4*)(p + 16);
        Whf[j][kq] = pack8(t);
      }
    f32x4 bxv[8];
#pragma unroll
    for (int j = 0; j < 8; ++j) bxv[j] = *(const f32x4*)(bx + j * 16 + 4 * q);

    const unsigned short* xb = xbf + (long)(blockIdx.x * 16 + m) * DD + 8 * q;

    unsigned w[8][2];
#pragma unroll
    for (int j = 0; j < 8; ++j) { w[j][0] = 0u; w[j][1] = 0u; }

    auto pref = [&](bf16x8 (&r)[4], int t) {
      const unsigned short* p = xb + (long)t * stepN;
#pragma unroll
      for (int kq = 0; kq < 4; ++kq) r[kq] = *(const bf16x8*)(p + 32 * kq);
    };

    auto step = [&](const bf16x8 (&xf)[4], int t) {
      // backpressure: slot t&3 holds step t-4; wait until both consumers ate it
      if (t >= SDEPTH) {
        const unsigned need = (unsigned)(t - SDEPTH + 1);
        while (consumed[0] < need || consumed[1] < need)
          __builtin_amdgcn_s_sleep(1);
        asm volatile("" ::: "memory");
      }
      // acc = bx + Wx x_t^T (h-independent, fills the pipe)
      f32x4 acc[8];
#pragma unroll
      for (int j = 0; j < 8; ++j)
        acc[j] = __builtin_amdgcn_mfma_f32_16x16x32_bf16(Wxf[j][0], xf[0], bxv[j], 0, 0, 0);
#pragma unroll
      for (int kq = 1; kq < 4; ++kq)
#pragma unroll
        for (int j = 0; j < 8; ++j)
          acc[j] = __builtin_amdgcn_mfma_f32_16x16x32_bf16(Wxf[j][kq], xf[kq], acc[j], 0, 0, 0);
      // acc += Wh h^T (feedback B-frags are last step's packed D quads)
#pragma unroll
      for (int kq = 0; kq < 4; ++kq) {
        u32x4 bw;
        bw[0] = w[2 * kq][0];     bw[1] = w[2 * kq][1];
        bw[2] = w[2 * kq + 1][0]; bw[3] = w[2 * kq + 1][1];
        bf16x8 bf = __builtin_bit_cast(bf16x8, bw);
#pragma unroll
        for (int j = 0; j < 8; ++j)
          acc[j] = __builtin_amdgcn_mfma_f32_16x16x32_bf16(Whf[j][kq], bf, acc[j], 0, 0, 0);
      }
      // relu, repack feedback, publish fp32 h to the LDS ring
      float* hp = &hbuf[t & (SDEPTH - 1)][m * LROW + 4 * q];
#pragma unroll
      for (int j = 0; j < 8; ++j) {
        f32x4 hv;
#pragma unroll
        for (int rr = 0; rr < 4; ++rr) hv[rr] = fmaxf(acc[j][rr], 0.f);
        w[j][0] = cvtpk_bf16(hv[0], hv[1]);
        w[j][1] = cvtpk_bf16(hv[2], hv[3]);
        *(f32x4*)(hp + j * 16) = hv;            // ds_write_b128, 16B-aligned
      }
      asm volatile("s_waitcnt lgkmcnt(0)" ::: "memory");
      if (lane == 0) produced = (unsigned)(t + 1);
    };

    bf16x8 rA[4], rB[4], rC[4], rD[4];   // 4-deep named x prefetch ring
    pref(rA, 0); pref(rB, 1); pref(rC, 2); pref(rD, 3);

#pragma unroll 1
    for (int t = 0; t < T_STEPS; t += 4) {
      step(rA, t);     pref(rA, t + 4 < T_STEPS ? t + 4 : T_STEPS - 1);
      step(rB, t + 1); pref(rB, t + 5 < T_STEPS ? t + 5 : T_STEPS - 1);
      step(rC, t + 2); pref(rC, t + 6 < T_STEPS ? t + 6 : T_STEPS - 1);
      step(rD, t + 3); pref(rD, t + 7 < T_STEPS ? t + 7 : T_STEPS - 1);
    }
  } else {
    // ------------------------------ consumers: LDS -> global stores ------
    const int c     = wave - 1;                 // 0 or 1: rows [c*8, c*8+8)
    const int rbase = c * 8 + (lane >> 5);      // this lane's first row
    const int col   = (lane & 31) * 4;          // 32 lanes cover a 512B row
    float* Hbase = H + (long)(blockIdx.x * 16) * DD;

#pragma unroll 2                                // renames v-regs: 2x WAR distance
    for (int t = 0; t < T_STEPS; ++t) {
      while (produced < (unsigned)(t + 1)) __builtin_amdgcn_s_sleep(1);
      asm volatile("" ::: "memory");
      const float* lb = &hbuf[t & (SDEPTH - 1)][0];
      f32x4 v0 = *(const f32x4*)(lb + (rbase + 0) * LROW + col);
      f32x4 v1 = *(const f32x4*)(lb + (rbase + 2) * LROW + col);
      f32x4 v2 = *(const f32x4*)(lb + (rbase + 4) * LROW + col);
      f32x4 v3 = *(const f32x4*)(lb + (rbase + 6) * LROW + col);
      asm volatile("s_waitcnt lgkmcnt(0)" ::: "memory");
      if (lane == 0) consumed[c] = (unsigned)(t + 1);   // slot reusable
      float* gp = Hbase + (long)t * stepN + (long)rbase * DD + col;
      *(f32x4*)(gp + 0 * DD) = v0;
      *(f32x4*)(gp + 2 * DD) = v1;
      *(f32x4*)(gp + 4 * DD) = v2;
      *(f32x4*)(gp + 6 * DD) = v3;
    }
  }
}

// ---------------------------------------------------------------------------
extern "C" void kernel_launch(void* const* d_in, const int* in_sizes, int n_in,
                              void* d_out, int out_size, void* d_ws, size_t ws_size,
                              hipStream_t stream) {
  const float* x  = (const float*)d_in[0];   // (T,N,C)
  const float* Wx = (const float*)d_in[1];   // (D,C)
  const float* bx = (const float*)d_in[2];   // (D)
  const float* Wh = (const float*)d_in[3];   // (D,D)
  const float* Wy = (const float*)d_in[4];   // (K,D)
  const float* by = (const float*)d_in[5];   // (K)

  float* Y = (float*)d_out;        // all_y: [T][N][K]
  float* H = (float*)d_out + TND;  // all_h: [T][N][D]

  // bf16 x staging lives in the Y region (32MB in 64MB); GEMM-Y overwrites
  // it only after the scan has fully consumed it (same-stream ordering).
  unsigned short* xbf = (unsigned short*)Y;

  const int ntiles = T_STEPS * NBATCH / 16;  // 8192 row-tiles

  cvt_x_bf16<<<2048, 256, 0, stream>>>(x, xbf, TND / 8);               // x -> bf16
  rnn_scan_fused<<<NBATCH / 16, 192, 0, stream>>>(xbf, Wx, bx, Wh, H); // -> all_h
  gemm128_yT<<<512, 256, 0, stream>>>(H, Wy, by, Y, ntiles);           // -> all_y
}

// Round 8
// 523.398 us; speedup vs baseline: 1.7284x; 1.7284x over previous
//
#include <hip/hip_runtime.h>

static constexpr int T_STEPS = 512;
static constexpr int NBATCH  = 256;
static constexpr int DD      = 128;                         // C = D = K = 128
static constexpr long TND    = (long)T_STEPS * NBATCH * DD; // elems per output tensor

typedef short bf16x8 __attribute__((ext_vector_type(8)));   // 8 bf16 in 4 VGPRs
typedef float f32x4  __attribute__((ext_vector_type(4)));
typedef unsigned u32x4 __attribute__((ext_vector_type(4)));

__device__ inline unsigned short f2bf(float f) {            // RNE fp32 -> bf16
  unsigned u = __builtin_bit_cast(unsigned, f);
  unsigned r = u + 0x7FFFu + ((u >> 16) & 1u);
  return (unsigned short)(r >> 16);
}

__device__ inline bf16x8 pack8(const float* s) {
  bf16x8 v;
#pragma unroll
  for (int i = 0; i < 8; ++i) v[i] = (short)f2bf(s[i]);
  return v;
}

// v_cvt_pk_bf16_f32: D.lo = bf16(lo), D.hi = bf16(hi), RNE (gfx950).
__device__ __forceinline__ unsigned cvtpk_bf16(float lo, float hi) {
  unsigned r;
  asm("v_cvt_pk_bf16_f32 %0, %1, %2" : "=v"(r) : "v"(lo), "v"(hi));
  return r;
}

// ---------------------------------------------------------------------------
// Pre-pass: x (f32, 64MB) -> bf16 (32MB), RNE. Output parked in the Y region
// (overwritten by GEMM-Y only after the scan consumed it, same stream).
// ---------------------------------------------------------------------------
__global__ __launch_bounds__(256) void cvt_x_bf16(
    const float* __restrict__ x, unsigned short* __restrict__ xb, long n8) {
  long i = (long)blockIdx.x * 256 + threadIdx.x;
  const long stride = (long)gridDim.x * 256;
  for (; i < n8; i += stride) {
    const float* p = x + i * 8;
    f32x4 a = *(const f32x4*)p, b = *(const f32x4*)(p + 4);
    u32x4 u;
    u[0] = cvtpk_bf16(a[0], a[1]); u[1] = cvtpk_bf16(a[2], a[3]);
    u[2] = cvtpk_bf16(b[0], b[1]); u[3] = cvtpk_bf16(b[2], b[3]);
    *(u32x4*)(xb + i * 8) = u;
  }
}

// ---------------------------------------------------------------------------
// Phase 3: Y[M x 128] = A[M x 128] @ Wy^T + by, Wy as the A-operand so the
// D-layout gives per-lane contiguous k -> 8 f32x4 stores/tile. Bias = C-init.
// ---------------------------------------------------------------------------
__global__ __launch_bounds__(256) void gemm128_yT(
    const float* __restrict__ A, const float* __restrict__ W,
    const float* __restrict__ bias, float* __restrict__ O, int ntiles) {
  const int lane = threadIdx.x & 63;
  const int wib  = threadIdx.x >> 6;     // wave in block (0..3)
  const int m    = lane & 15;
  const int q    = lane >> 4;

  bf16x8 Wf[8][4];
#pragma unroll
  for (int j = 0; j < 8; ++j)
#pragma unroll
    for (int kq = 0; kq < 4; ++kq) {
      const float* p = W + (j * 16 + m) * DD + kq * 32 + q * 8;
      float t[8];
      *(float4*)&t[0] = *(const float4*)p;
      *(float4*)&t[4] = *(const float4*)(p + 4);
      Wf[j][kq] = pack8(t);
    }
  f32x4 bv4[8];
#pragma unroll
  for (int j = 0; j < 8; ++j) bv4[j] = *(const f32x4*)(bias + j * 16 + 4 * q);

  const int wglobal = blockIdx.x * 4 + wib;
  const int nwaves  = gridDim.x * 4;
  for (int tile = wglobal; tile < ntiles; tile += nwaves) {
    const long r0 = (long)tile * 16;

    bf16x8 af[4];
#pragma unroll
    for (int kq = 0; kq < 4; ++kq) {
      const float* p = A + (r0 + m) * DD + kq * 32 + q * 8;
      float t[8];
      *(float4*)&t[0] = *(const float4*)p;
      *(float4*)&t[4] = *(const float4*)(p + 4);
      af[kq] = pack8(t);
    }
    f32x4 acc[8];
#pragma unroll
    for (int j = 0; j < 8; ++j)
      acc[j] = __builtin_amdgcn_mfma_f32_16x16x32_bf16(Wf[j][0], af[0], bv4[j], 0, 0, 0);
#pragma unroll
    for (int kq = 1; kq < 4; ++kq)
#pragma unroll
      for (int j = 0; j < 8; ++j)
        acc[j] = __builtin_amdgcn_mfma_f32_16x16x32_bf16(Wf[j][kq], af[kq], acc[j], 0, 0, 0);

    float* op = O + (r0 + m) * DD + 4 * q;
#pragma unroll
    for (int j = 0; j < 8; ++j)
      *(f32x4*)(op + j * 16) = acc[j];
  }
}

// ---------------------------------------------------------------------------
// Phase 1+2 FUSED scan, v5: D-SPLIT ACROSS 4 WAVES. Theory: one wave caps at
// ~20 GB/s of in-flight memory (R2 measured exactly the ceiling); the step
// needs 12KB, so split compute AND memory 4 ways. Wave wv owns d-slice
// j in {2wv, 2wv+1}: 16 MFMA + 4 x-loads + 2 h-stores per step per wave.
// Step-boundary exchange exploits the kappa layout: the u32x4 each wave
// cvt_pk-packs from its two D-quads IS the B-fragment bf[kq=wv] every wave
// needs next step — 1 ds_write_b128 + raw s_barrier (lgkmcnt(0) only; x
// prefetch and h stores stay in flight, NO vmcnt drain) + 4 ds_read_b128.
// Double-buffered by parity; one barrier/step is sufficient (reads of buf p
// finish before each wave's own lgkmcnt(0)+barrier; next write to p comes
// two barriers later). Bitwise-identical arithmetic to R6.
// ---------------------------------------------------------------------------
__global__ __launch_bounds__(256, 1) void rnn_scan_fused(
    const unsigned short* __restrict__ xbf, const float* __restrict__ Wx,
    const float* __restrict__ bx, const float* __restrict__ Wh,
    float* __restrict__ H /* [T][N][128] output: all_h */) {
  __shared__ __align__(16) u32x4 xchg[2][4][64];   // 8KB h-exchange, 2 parities

  const int wv   = threadIdx.x >> 6;   // wave 0..3 owns j = {2wv, 2wv+1}
  const int lane = threadIdx.x & 63;
  const int m = lane & 15;             // batch row within the block's 16
  const int q = lane >> 4;             // quad

  xchg[1][wv][lane] = (u32x4){0u, 0u, 0u, 0u};   // step 0 reads parity 1: h_-1=0
  __syncthreads();

  const int jj0 = 2 * wv;

  // Wx A-frags (standard slot k = 32kq + 8q + s), own j's only
  bf16x8 Wxf[2][4];
#pragma unroll
  for (int jl = 0; jl < 2; ++jl)
#pragma unroll
    for (int kq = 0; kq < 4; ++kq) {
      const float* p = Wx + ((jj0 + jl) * 16 + m) * DD + kq * 32 + q * 8;
      float t[8];
      *(float4*)&t[0] = *(const float4*)p;
      *(float4*)&t[4] = *(const float4*)(p + 4);
      Wxf[jl][kq] = pack8(t);
    }
  // Wh A-frags with the q-dependent kappa gather, own j's only
  bf16x8 Whf[2][4];
#pragma unroll
  for (int jl = 0; jl < 2; ++jl)
#pragma unroll
    for (int kq = 0; kq < 4; ++kq) {
      const float* p = Wh + ((jj0 + jl) * 16 + m) * DD + kq * 32 + 4 * q;
      float t[8];
      *(float4*)&t[0] = *(const float4*)p;
      *(float4*)&t[4] = *(const float4*)(p + 16);
      Whf[jl][kq] = pack8(t);
    }
  f32x4 bxv[2];
#pragma unroll
  for (int jl = 0; jl < 2; ++jl)
    bxv[jl] = *(const f32x4*)(bx + (jj0 + jl) * 16 + 4 * q);

  const long stepN = (long)NBATCH * DD;
  const unsigned short* xb = xbf + (long)(blockIdx.x * 16 + m) * DD + 8 * q;
  float* hb = H + (long)(blockIdx.x * 16 + m) * DD;

  auto pref = [&](bf16x8 (&r)[4], int t) {     // 4 x 16B ready-to-use B-frags
    const unsigned short* p = xb + (long)t * stepN;
#pragma unroll
    for (int kq = 0; kq < 4; ++kq) r[kq] = *(const bf16x8*)(p + 32 * kq);
  };

  auto step = [&](const bf16x8 (&xf)[4], int t, int par) {
    // exchange reads (written by all waves at step t-1, parity par^1);
    // e[kq] IS bf[kq] — zero repack thanks to the kappa layout.
    u32x4 e0 = xchg[par ^ 1][0][lane];
    u32x4 e1 = xchg[par ^ 1][1][lane];
    u32x4 e2 = xchg[par ^ 1][2][lane];
    u32x4 e3 = xchg[par ^ 1][3][lane];

    // acc = bx + Wx x_t^T  (independent of the exchange: hides e-read latency)
    f32x4 a0 = __builtin_amdgcn_mfma_f32_16x16x32_bf16(Wxf[0][0], xf[0], bxv[0], 0, 0, 0);
    f32x4 a1 = __builtin_amdgcn_mfma_f32_16x16x32_bf16(Wxf[1][0], xf[0], bxv[1], 0, 0, 0);
#pragma unroll
    for (int kq = 1; kq < 4; ++kq) {
      a0 = __builtin_amdgcn_mfma_f32_16x16x32_bf16(Wxf[0][kq], xf[kq], a0, 0, 0, 0);
      a1 = __builtin_amdgcn_mfma_f32_16x16x32_bf16(Wxf[1][kq], xf[kq], a1, 0, 0, 0);
    }
    // acc += Wh h^T  (B-frags = the exchange vectors, compiler adds lgkmcnt)
    bf16x8 b0 = __builtin_bit_cast(bf16x8, e0), b1 = __builtin_bit_cast(bf16x8, e1);
    bf16x8 b2 = __builtin_bit_cast(bf16x8, e2), b3 = __builtin_bit_cast(bf16x8, e3);
    a0 = __builtin_amdgcn_mfma_f32_16x16x32_bf16(Whf[0][0], b0, a0, 0, 0, 0);
    a1 = __builtin_amdgcn_mfma_f32_16x16x32_bf16(Whf[1][0], b0, a1, 0, 0, 0);
    a0 = __builtin_amdgcn_mfma_f32_16x16x32_bf16(Whf[0][1], b1, a0, 0, 0, 0);
    a1 = __builtin_amdgcn_mfma_f32_16x16x32_bf16(Whf[1][1], b1, a1, 0, 0, 0);
    a0 = __builtin_amdgcn_mfma_f32_16x16x32_bf16(Whf[0][2], b2, a0, 0, 0, 0);
    a1 = __builtin_amdgcn_mfma_f32_16x16x32_bf16(Whf[1][2], b2, a1, 0, 0, 0);
    a0 = __builtin_amdgcn_mfma_f32_16x16x32_bf16(Whf[0][3], b3, a0, 0, 0, 0);
    a1 = __builtin_amdgcn_mfma_f32_16x16x32_bf16(Whf[1][3], b3, a1, 0, 0, 0);

    // relu; publish own slice: global (fire-and-forget) + exchange
    f32x4 h0, h1;
#pragma unroll
    for (int r = 0; r < 4; ++r) { h0[r] = fmaxf(a0[r], 0.f); h1[r] = fmaxf(a1[r], 0.f); }
    float* hp = hb + (long)t * stepN;
    *(f32x4*)(hp + (jj0 + 0) * 16 + 4 * q) = h0;
    *(f32x4*)(hp + (jj0 + 1) * 16 + 4 * q) = h1;
    u32x4 own;
    own[0] = cvtpk_bf16(h0[0], h0[1]); own[1] = cvtpk_bf16(h0[2], h0[3]);
    own[2] = cvtpk_bf16(h1[0], h1[1]); own[3] = cvtpk_bf16(h1[2], h1[3]);
    xchg[par][wv][lane] = own;

    asm volatile("s_waitcnt lgkmcnt(0)" ::: "memory");  // ds_write visible; NO vmcnt drain
    __builtin_amdgcn_s_barrier();
    __builtin_amdgcn_sched_barrier(0);                  // pin next step's e-reads after barrier
  };

  bf16x8 rA[4], rB[4], rC[4], rD[4];   // 4-deep named x prefetch ring
  pref(rA, 0); pref(rB, 1); pref(rC, 2); pref(rD, 3);

#pragma unroll 1
  for (int t = 0; t < T_STEPS; t += 4) {
    step(rA, t, 0);     pref(rA, t + 4 < T_STEPS ? t + 4 : T_STEPS - 1);
    step(rB, t + 1, 1); pref(rB, t + 5 < T_STEPS ? t + 5 : T_STEPS - 1);
    step(rC, t + 2, 0); pref(rC, t + 6 < T_STEPS ? t + 6 : T_STEPS - 1);
    step(rD, t + 3, 1); pref(rD, t + 7 < T_STEPS ? t + 7 : T_STEPS - 1);
  }
}

// ---------------------------------------------------------------------------
extern "C" void kernel_launch(void* const* d_in, const int* in_sizes, int n_in,
                              void* d_out, int out_size, void* d_ws, size_t ws_size,
                              hipStream_t stream) {
  const float* x  = (const float*)d_in[0];   // (T,N,C)
  const float* Wx = (const float*)d_in[1];   // (D,C)
  const float* bx = (const float*)d_in[2];   // (D)
  const float* Wh = (const float*)d_in[3];   // (D,D)
  const float* Wy = (const float*)d_in[4];   // (K,D)
  const float* by = (const float*)d_in[5];   // (K)

  float* Y = (float*)d_out;        // all_y: [T][N][K]
  float* H = (float*)d_out + TND;  // all_h: [T][N][D]

  // bf16 x staging lives in the Y region (32MB in 64MB); GEMM-Y overwrites
  // it only after the scan has fully consumed it (same-stream ordering).
  unsigned short* xbf = (unsigned short*)Y;

  const int ntiles = T_STEPS * NBATCH / 16;  // 8192 row-tiles

  cvt_x_bf16<<<2048, 256, 0, stream>>>(x, xbf, TND / 8);               // x -> bf16
  rnn_scan_fused<<<NBATCH / 16, 256, 0, stream>>>(xbf, Wx, bx, Wh, H); // -> all_h
  gemm128_yT<<<512, 256, 0, stream>>>(H, Wy, by, Y, ntiles);           // -> all_y
}